// Round 1
// baseline (861.891 us; speedup 1.0000x reference)
//
#include <hip/hip_runtime.h>
#include <math.h>

#define N_NODES 20000
#define F 128
#define NRBF 20
#define E_EDGES 320000
#define F3 (3 * F)   // 384

__device__ __forceinline__ float silu_f(float x) {
    return x / (1.0f + __expf(-x));
}

// ---------------------------------------------------------------------------
// Kernel A: per-node MLP  h[n,o] = silu(s[n]@W1 + b1) @ W2 + b2   (o in [0,384))
// block = 128 threads (thread = hidden/feature index g), NTILE_A nodes/block
// ---------------------------------------------------------------------------
#define NTILE_A 8
__global__ __launch_bounds__(128) void node_mlp_kernel(
    const float* __restrict__ s, const float* __restrict__ W1, const float* __restrict__ b1,
    const float* __restrict__ W2, const float* __restrict__ b2, float* __restrict__ h)
{
    __shared__ float sl[NTILE_A][F];
    __shared__ float hid[NTILE_A][F];
    const int g = threadIdx.x;
    const int n0 = blockIdx.x * NTILE_A;

    #pragma unroll
    for (int t = 0; t < NTILE_A; ++t)
        sl[t][g] = s[(size_t)(n0 + t) * F + g];
    __syncthreads();

    // stage 1: hid = silu(s @ W1 + b1)
    float acc[NTILE_A];
    #pragma unroll
    for (int t = 0; t < NTILE_A; ++t) acc[t] = 0.0f;
    for (int f = 0; f < F; ++f) {
        float w = W1[f * F + g];
        #pragma unroll
        for (int t = 0; t < NTILE_A; ++t) acc[t] += sl[t][f] * w;
    }
    float bb = b1[g];
    #pragma unroll
    for (int t = 0; t < NTILE_A; ++t) hid[t][g] = silu_f(acc[t] + bb);
    __syncthreads();

    // stage 2: h = hid @ W2 + b2  (each thread owns outputs g, g+128, g+256)
    float acc2[3][NTILE_A];
    #pragma unroll
    for (int o3 = 0; o3 < 3; ++o3)
        #pragma unroll
        for (int t = 0; t < NTILE_A; ++t) acc2[o3][t] = 0.0f;

    for (int k = 0; k < F; ++k) {
        #pragma unroll
        for (int o3 = 0; o3 < 3; ++o3) {
            float w2 = W2[k * F3 + o3 * F + g];
            #pragma unroll
            for (int t = 0; t < NTILE_A; ++t) acc2[o3][t] += hid[t][k] * w2;
        }
    }
    #pragma unroll
    for (int o3 = 0; o3 < 3; ++o3) {
        float bv = b2[o3 * F + g];
        #pragma unroll
        for (int t = 0; t < NTILE_A; ++t)
            h[(size_t)(n0 + t) * F3 + o3 * F + g] = acc2[o3][t] + bv;
    }
}

// ---------------------------------------------------------------------------
// Kernel B: per-edge filter + scatter-add.
//   x = rbf[e]@Wr + br; W = 0.5*(cos(pi*x/5)+1)*(x<5); split = h[j[e]]*W
//   s_agg[i[e]] += split[:128]
//   v_agg[i[e]][f][d] += split[128+f]*dir[e][d] + split[256+f]*v[j[e]][f][d]
// block = 384 threads, ETILE edges per block
// ---------------------------------------------------------------------------
#define ETILE 16
__global__ __launch_bounds__(384) void edge_kernel(
    const float* __restrict__ rbf, const float* __restrict__ dir,
    const int* __restrict__ i_index, const int* __restrict__ j_index,
    const float* __restrict__ Wr, const float* __restrict__ br,
    const float* __restrict__ h, const float* __restrict__ v,
    float* __restrict__ s_agg, float* __restrict__ v_agg)
{
    __shared__ float rbl[ETILE][NRBF];     // per-edge rbf
    __shared__ float dirl[ETILE][3];
    __shared__ int   il[ETILE];
    __shared__ int   jl[ETILE];
    __shared__ float spl[ETILE][2 * F];    // Wvs at [f], Wvv at [F+f]

    const int t = threadIdx.x;             // 0..383
    const int e0 = blockIdx.x * ETILE;

    if (t < ETILE * NRBF) ((float*)rbl)[t] = rbf[(size_t)e0 * NRBF + t];
    if (t < ETILE * 3)    ((float*)dirl)[t] = dir[(size_t)e0 * 3 + t];
    if (t < ETILE)        { il[t] = i_index[e0 + t]; jl[t] = j_index[e0 + t]; }
    __syncthreads();

    // thread t owns output channel o = t of the 384-wide filter
    float wrc[NRBF];
    #pragma unroll
    for (int k = 0; k < NRBF; ++k) wrc[k] = Wr[k * F3 + t];
    const float bro = br[t];

    // phase 1: filter + s-scatter; stash v-weights in LDS
    for (int e = 0; e < ETILE; ++e) {
        float x = bro;
        #pragma unroll
        for (int k = 0; k < NRBF; ++k) x += rbl[e][k] * wrc[k];
        float wcut = (x < 5.0f) ? 0.5f * (__cosf(x * 0.6283185307179586f) + 1.0f) : 0.0f;
        float sp = h[(size_t)jl[e] * F3 + t] * wcut;
        if (t < F) {
            atomicAdd(&s_agg[(size_t)il[e] * F + t], sp);
        } else {
            spl[e][t - F] = sp;
        }
    }
    __syncthreads();

    // phase 2: v-scatter. t enumerates (f,d): t = f*3+d, and v layout n*384 + f*3 + d
    const int f = t / 3;
    const int d = t - 3 * f;
    for (int e = 0; e < ETILE; ++e) {
        float vj = v[(size_t)jl[e] * F3 + t];
        float delta = spl[e][f] * dirl[e][d] + spl[e][F + f] * vj;
        atomicAdd(&v_agg[(size_t)il[e] * F3 + t], delta);
    }
}

// ---------------------------------------------------------------------------
// Kernel C: per-node update block.
//   Uv = v_agg@WU + bU ; Vv = v_agg@WV + bV (per direction)
//   m = silu([||Vv||, s_agg]@M1 + bm1)@M2 + bm2
//   s_out = s_agg + sum_d(Uv*Vv)*a_sv + a_ss ; v_out = v_agg + a_vv*Uv
// block = 128 threads (thread = feature g), T_C nodes/block
// ---------------------------------------------------------------------------
#define T_C 4
__global__ __launch_bounds__(128) void update_kernel(
    const float* __restrict__ s_agg, const float* __restrict__ v_agg,
    const float* __restrict__ WU, const float* __restrict__ bU,
    const float* __restrict__ WV, const float* __restrict__ bV,
    const float* __restrict__ M1, const float* __restrict__ bm1,
    const float* __restrict__ M2, const float* __restrict__ bm2,
    float* __restrict__ s_out, float* __restrict__ v_out)
{
    __shared__ float vl[T_C][F][3];
    __shared__ float inl[T_C][2 * F];   // [Vv_norm (128), s (128)]
    __shared__ float hidl[T_C][F];

    const int g = threadIdx.x;
    const int n0 = blockIdx.x * T_C;

    for (int idx = g; idx < T_C * F3; idx += 128)
        ((float*)vl)[idx] = v_agg[(size_t)n0 * F3 + idx];
    #pragma unroll
    for (int t = 0; t < T_C; ++t)
        inl[t][F + g] = s_agg[(size_t)(n0 + t) * F + g];
    __syncthreads();

    // Uv / Vv (feature g, all 3 directions, T_C nodes)
    float uacc[T_C][3], vacc[T_C][3];
    #pragma unroll
    for (int t = 0; t < T_C; ++t)
        #pragma unroll
        for (int d = 0; d < 3; ++d) { uacc[t][d] = 0.0f; vacc[t][d] = 0.0f; }

    for (int f = 0; f < F; ++f) {
        float wu = WU[f * F + g];
        float wv = WV[f * F + g];
        #pragma unroll
        for (int t = 0; t < T_C; ++t) {
            #pragma unroll
            for (int d = 0; d < 3; ++d) {
                float vv = vl[t][f][d];
                uacc[t][d] += vv * wu;
                vacc[t][d] += vv * wv;
            }
        }
    }
    float bu = bU[g], bv = bV[g];
    #pragma unroll
    for (int t = 0; t < T_C; ++t) {
        #pragma unroll
        for (int d = 0; d < 3; ++d) { uacc[t][d] += bu; vacc[t][d] += bv; }
        inl[t][g] = sqrtf(vacc[t][0] * vacc[t][0] + vacc[t][1] * vacc[t][1] +
                          vacc[t][2] * vacc[t][2]);
    }
    __syncthreads();

    // MLP stage 1: hid = silu([Vv_norm, s]@M1 + bm1)
    float hacc[T_C];
    #pragma unroll
    for (int t = 0; t < T_C; ++t) hacc[t] = 0.0f;
    for (int k = 0; k < 2 * F; ++k) {
        float m1 = M1[k * F + g];
        #pragma unroll
        for (int t = 0; t < T_C; ++t) hacc[t] += inl[t][k] * m1;
    }
    float bh = bm1[g];
    #pragma unroll
    for (int t = 0; t < T_C; ++t) hidl[t][g] = silu_f(hacc[t] + bh);
    __syncthreads();

    // MLP stage 2: m = hid@M2 + bm2 ; thread owns o = g, g+128, g+256
    float macc[3][T_C];
    #pragma unroll
    for (int o3 = 0; o3 < 3; ++o3)
        #pragma unroll
        for (int t = 0; t < T_C; ++t) macc[o3][t] = 0.0f;
    for (int k = 0; k < F; ++k) {
        #pragma unroll
        for (int o3 = 0; o3 < 3; ++o3) {
            float m2 = M2[k * F3 + o3 * F + g];
            #pragma unroll
            for (int t = 0; t < T_C; ++t) macc[o3][t] += hidl[t][k] * m2;
        }
    }
    const float bvv = bm2[g], bsv = bm2[F + g], bss = bm2[2 * F + g];

    #pragma unroll
    for (int t = 0; t < T_C; ++t) {
        float a_vv = macc[0][t] + bvv;
        float a_sv = macc[1][t] + bsv;
        float a_ss = macc[2][t] + bss;
        float dotuv = uacc[t][0] * vacc[t][0] + uacc[t][1] * vacc[t][1] +
                      uacc[t][2] * vacc[t][2];
        s_out[(size_t)(n0 + t) * F + g] = inl[t][F + g] + dotuv * a_sv + a_ss;
        #pragma unroll
        for (int d = 0; d < 3; ++d)
            v_out[(size_t)(n0 + t) * F3 + g * 3 + d] = vl[t][g][d] + a_vv * uacc[t][d];
    }
}

// ---------------------------------------------------------------------------
extern "C" void kernel_launch(void* const* d_in, const int* in_sizes, int n_in,
                              void* d_out, int out_size, void* d_ws, size_t ws_size,
                              hipStream_t stream) {
    const float* s    = (const float*)d_in[0];
    const float* v    = (const float*)d_in[1];
    const float* rbf  = (const float*)d_in[2];
    const float* dir  = (const float*)d_in[3];
    const float* W1   = (const float*)d_in[4];
    const float* b1   = (const float*)d_in[5];
    const float* W2   = (const float*)d_in[6];
    const float* b2   = (const float*)d_in[7];
    const float* Wr   = (const float*)d_in[8];
    const float* br   = (const float*)d_in[9];
    const float* WU   = (const float*)d_in[10];
    const float* bU   = (const float*)d_in[11];
    const float* WV   = (const float*)d_in[12];
    const float* bV   = (const float*)d_in[13];
    const float* M1   = (const float*)d_in[14];
    const float* bm1  = (const float*)d_in[15];
    const float* M2   = (const float*)d_in[16];
    const float* bm2  = (const float*)d_in[17];
    const int* i_index = (const int*)d_in[18];
    const int* j_index = (const int*)d_in[19];

    float* out_s = (float*)d_out;                     // N*F
    float* out_v = out_s + (size_t)N_NODES * F;       // N*F*3

    float* h     = (float*)d_ws;                      // N*384
    float* s_agg = h + (size_t)N_NODES * F3;          // N*128
    float* v_agg = s_agg + (size_t)N_NODES * F;       // N*384

    // init aggregation buffers with the input s / v (ws is poisoned each call)
    hipMemcpyAsync(s_agg, s, sizeof(float) * (size_t)N_NODES * F,
                   hipMemcpyDeviceToDevice, stream);
    hipMemcpyAsync(v_agg, v, sizeof(float) * (size_t)N_NODES * F3,
                   hipMemcpyDeviceToDevice, stream);

    node_mlp_kernel<<<N_NODES / NTILE_A, 128, 0, stream>>>(s, W1, b1, W2, b2, h);
    edge_kernel<<<E_EDGES / ETILE, 384, 0, stream>>>(rbf, dir, i_index, j_index,
                                                     Wr, br, h, v, s_agg, v_agg);
    update_kernel<<<N_NODES / T_C, 128, 0, stream>>>(s_agg, v_agg, WU, bU, WV, bV,
                                                     M1, bm1, M2, bm2, out_s, out_v);
}

// Round 2
// 567.142 us; speedup vs baseline: 1.5197x; 1.5197x over previous
//
#include <hip/hip_runtime.h>
#include <math.h>

#define N_NODES 20000
#define F 128
#define NRBF 20
#define E_EDGES 320000
#define F3 (3 * F)   // 384

__device__ __forceinline__ float silu_f(float x) {
    return x / (1.0f + __expf(-x));
}

// ---------------------------------------------------------------------------
// Kernel A: per-node MLP  h[n,o] = silu(s[n]@W1 + b1) @ W2 + b2   (o in [0,384))
// ---------------------------------------------------------------------------
#define NTILE_A 8
__global__ __launch_bounds__(128) void node_mlp_kernel(
    const float* __restrict__ s, const float* __restrict__ W1, const float* __restrict__ b1,
    const float* __restrict__ W2, const float* __restrict__ b2, float* __restrict__ h)
{
    __shared__ float sl[NTILE_A][F];
    __shared__ float hid[NTILE_A][F];
    const int g = threadIdx.x;
    const int n0 = blockIdx.x * NTILE_A;

    #pragma unroll
    for (int t = 0; t < NTILE_A; ++t)
        sl[t][g] = s[(size_t)(n0 + t) * F + g];
    __syncthreads();

    float acc[NTILE_A];
    #pragma unroll
    for (int t = 0; t < NTILE_A; ++t) acc[t] = 0.0f;
    for (int f = 0; f < F; ++f) {
        float w = W1[f * F + g];
        #pragma unroll
        for (int t = 0; t < NTILE_A; ++t) acc[t] += sl[t][f] * w;
    }
    float bb = b1[g];
    #pragma unroll
    for (int t = 0; t < NTILE_A; ++t) hid[t][g] = silu_f(acc[t] + bb);
    __syncthreads();

    float acc2[3][NTILE_A];
    #pragma unroll
    for (int o3 = 0; o3 < 3; ++o3)
        #pragma unroll
        for (int t = 0; t < NTILE_A; ++t) acc2[o3][t] = 0.0f;

    for (int k = 0; k < F; ++k) {
        #pragma unroll
        for (int o3 = 0; o3 < 3; ++o3) {
            float w2 = W2[k * F3 + o3 * F + g];
            #pragma unroll
            for (int t = 0; t < NTILE_A; ++t) acc2[o3][t] += hid[t][k] * w2;
        }
    }
    #pragma unroll
    for (int o3 = 0; o3 < 3; ++o3) {
        float bv = b2[o3 * F + g];
        #pragma unroll
        for (int t = 0; t < NTILE_A; ++t)
            h[(size_t)(n0 + t) * F3 + o3 * F + g] = acc2[o3][t] + bv;
    }
}

// ---------------------------------------------------------------------------
// CSR build: histogram -> exclusive scan -> scatter
// ---------------------------------------------------------------------------
__global__ __launch_bounds__(256) void hist_kernel(const int* __restrict__ i_index,
                                                   int* __restrict__ counts)
{
    int e = blockIdx.x * 256 + threadIdx.x;
    if (e < E_EDGES) atomicAdd(&counts[i_index[e]], 1);
}

#define SCAN_T 1024
__global__ __launch_bounds__(SCAN_T) void scan_kernel(const int* __restrict__ counts,
                                                      int* __restrict__ row_start,
                                                      int* __restrict__ cursor)
{
    __shared__ int buf[SCAN_T];
    __shared__ int carry_s;
    const int tid = threadIdx.x;
    if (tid == 0) carry_s = 0;
    __syncthreads();
    const int nchunk = (N_NODES + SCAN_T - 1) / SCAN_T;
    for (int c = 0; c < nchunk; ++c) {
        int idx = c * SCAN_T + tid;
        int val = (idx < N_NODES) ? counts[idx] : 0;
        buf[tid] = val;
        __syncthreads();
        for (int off = 1; off < SCAN_T; off <<= 1) {
            int t = (tid >= off) ? buf[tid - off] : 0;
            __syncthreads();
            buf[tid] += t;
            __syncthreads();
        }
        int excl = carry_s + buf[tid] - val;   // reads old carry
        if (idx < N_NODES) { row_start[idx] = excl; cursor[idx] = excl; }
        __syncthreads();
        if (tid == SCAN_T - 1) carry_s += buf[SCAN_T - 1];
        __syncthreads();
    }
    if (tid == 0) row_start[N_NODES] = carry_s;
}

__global__ __launch_bounds__(256) void scatter_kernel(const int* __restrict__ i_index,
                                                      int* __restrict__ cursor,
                                                      int* __restrict__ edge_ids)
{
    int e = blockIdx.x * 256 + threadIdx.x;
    if (e < E_EDGES) {
        int pos = atomicAdd(&cursor[i_index[e]], 1);
        edge_ids[pos] = e;
    }
}

// ---------------------------------------------------------------------------
// Kernel B': per-destination-node aggregation (no atomics).
// Block = 128 threads, one node. Thread f owns s[f] and v[f][0..2] accumulators.
// Filter channels f, 128+f, 256+f computed per-thread (Wr columns in regs).
//   s_agg[n] = s[n] + sum_e Ws ; v_agg[n] = v[n] + sum_e (Wvs*dir + Wvv*v[j])
// ---------------------------------------------------------------------------
__global__ __launch_bounds__(128) void agg_kernel(
    const float* __restrict__ s, const float* __restrict__ v,
    const float* __restrict__ rbf, const float* __restrict__ dir,
    const int* __restrict__ j_index,
    const float* __restrict__ Wr, const float* __restrict__ br,
    const float* __restrict__ h,
    const int* __restrict__ row_start, const int* __restrict__ edge_ids,
    float* __restrict__ s_agg, float* __restrict__ v_agg)
{
    const int f = threadIdx.x;
    const int n = blockIdx.x;

    float wr0[NRBF], wr1[NRBF], wr2[NRBF];
    #pragma unroll
    for (int k = 0; k < NRBF; ++k) {
        wr0[k] = Wr[k * F3 + f];
        wr1[k] = Wr[k * F3 + F + f];
        wr2[k] = Wr[k * F3 + 2 * F + f];
    }
    const float br0 = br[f], br1 = br[F + f], br2 = br[2 * F + f];

    float s_acc = s[(size_t)n * F + f];
    float v0 = v[(size_t)n * F3 + f * 3 + 0];
    float v1 = v[(size_t)n * F3 + f * 3 + 1];
    float v2 = v[(size_t)n * F3 + f * 3 + 2];

    const int beg = row_start[n];
    const int end = row_start[n + 1];
    const float cc = 0.6283185307179586f;   // pi/5

    for (int idx = beg; idx < end; ++idx) {
        const int e = edge_ids[idx];
        const int j = j_index[e];

        float x0 = br0, x1 = br1, x2 = br2;
        #pragma unroll
        for (int k = 0; k < NRBF; ++k) {
            float r = rbf[(size_t)e * NRBF + k];
            x0 += r * wr0[k];
            x1 += r * wr1[k];
            x2 += r * wr2[k];
        }
        float w0 = (x0 < 5.0f) ? 0.5f * (__cosf(x0 * cc) + 1.0f) : 0.0f;
        float w1 = (x1 < 5.0f) ? 0.5f * (__cosf(x1 * cc) + 1.0f) : 0.0f;
        float w2 = (x2 < 5.0f) ? 0.5f * (__cosf(x2 * cc) + 1.0f) : 0.0f;

        float hs  = h[(size_t)j * F3 + f]         * w0;
        float hvs = h[(size_t)j * F3 + F + f]     * w1;
        float hvv = h[(size_t)j * F3 + 2 * F + f] * w2;

        float dx = dir[(size_t)e * 3 + 0];
        float dy = dir[(size_t)e * 3 + 1];
        float dz = dir[(size_t)e * 3 + 2];

        float vj0 = v[(size_t)j * F3 + f * 3 + 0];
        float vj1 = v[(size_t)j * F3 + f * 3 + 1];
        float vj2 = v[(size_t)j * F3 + f * 3 + 2];

        s_acc += hs;
        v0 += hvs * dx + hvv * vj0;
        v1 += hvs * dy + hvv * vj1;
        v2 += hvs * dz + hvv * vj2;
    }

    s_agg[(size_t)n * F + f] = s_acc;
    v_agg[(size_t)n * F3 + f * 3 + 0] = v0;
    v_agg[(size_t)n * F3 + f * 3 + 1] = v1;
    v_agg[(size_t)n * F3 + f * 3 + 2] = v2;
}

// ---------------------------------------------------------------------------
// Kernel C: per-node update block (unchanged from R1).
// ---------------------------------------------------------------------------
#define T_C 4
__global__ __launch_bounds__(128) void update_kernel(
    const float* __restrict__ s_agg, const float* __restrict__ v_agg,
    const float* __restrict__ WU, const float* __restrict__ bU,
    const float* __restrict__ WV, const float* __restrict__ bV,
    const float* __restrict__ M1, const float* __restrict__ bm1,
    const float* __restrict__ M2, const float* __restrict__ bm2,
    float* __restrict__ s_out, float* __restrict__ v_out)
{
    __shared__ float vl[T_C][F][3];
    __shared__ float inl[T_C][2 * F];
    __shared__ float hidl[T_C][F];

    const int g = threadIdx.x;
    const int n0 = blockIdx.x * T_C;

    for (int idx = g; idx < T_C * F3; idx += 128)
        ((float*)vl)[idx] = v_agg[(size_t)n0 * F3 + idx];
    #pragma unroll
    for (int t = 0; t < T_C; ++t)
        inl[t][F + g] = s_agg[(size_t)(n0 + t) * F + g];
    __syncthreads();

    float uacc[T_C][3], vacc[T_C][3];
    #pragma unroll
    for (int t = 0; t < T_C; ++t)
        #pragma unroll
        for (int d = 0; d < 3; ++d) { uacc[t][d] = 0.0f; vacc[t][d] = 0.0f; }

    for (int f = 0; f < F; ++f) {
        float wu = WU[f * F + g];
        float wv = WV[f * F + g];
        #pragma unroll
        for (int t = 0; t < T_C; ++t) {
            #pragma unroll
            for (int d = 0; d < 3; ++d) {
                float vv = vl[t][f][d];
                uacc[t][d] += vv * wu;
                vacc[t][d] += vv * wv;
            }
        }
    }
    float bu = bU[g], bv = bV[g];
    #pragma unroll
    for (int t = 0; t < T_C; ++t) {
        #pragma unroll
        for (int d = 0; d < 3; ++d) { uacc[t][d] += bu; vacc[t][d] += bv; }
        inl[t][g] = sqrtf(vacc[t][0] * vacc[t][0] + vacc[t][1] * vacc[t][1] +
                          vacc[t][2] * vacc[t][2]);
    }
    __syncthreads();

    float hacc[T_C];
    #pragma unroll
    for (int t = 0; t < T_C; ++t) hacc[t] = 0.0f;
    for (int k = 0; k < 2 * F; ++k) {
        float m1 = M1[k * F + g];
        #pragma unroll
        for (int t = 0; t < T_C; ++t) hacc[t] += inl[t][k] * m1;
    }
    float bh = bm1[g];
    #pragma unroll
    for (int t = 0; t < T_C; ++t) hidl[t][g] = silu_f(hacc[t] + bh);
    __syncthreads();

    float macc[3][T_C];
    #pragma unroll
    for (int o3 = 0; o3 < 3; ++o3)
        #pragma unroll
        for (int t = 0; t < T_C; ++t) macc[o3][t] = 0.0f;
    for (int k = 0; k < F; ++k) {
        #pragma unroll
        for (int o3 = 0; o3 < 3; ++o3) {
            float m2 = M2[k * F3 + o3 * F + g];
            #pragma unroll
            for (int t = 0; t < T_C; ++t) macc[o3][t] += hidl[t][k] * m2;
        }
    }
    const float bvv = bm2[g], bsv = bm2[F + g], bss = bm2[2 * F + g];

    #pragma unroll
    for (int t = 0; t < T_C; ++t) {
        float a_vv = macc[0][t] + bvv;
        float a_sv = macc[1][t] + bsv;
        float a_ss = macc[2][t] + bss;
        float dotuv = uacc[t][0] * vacc[t][0] + uacc[t][1] * vacc[t][1] +
                      uacc[t][2] * vacc[t][2];
        s_out[(size_t)(n0 + t) * F + g] = inl[t][F + g] + dotuv * a_sv + a_ss;
        #pragma unroll
        for (int d = 0; d < 3; ++d)
            v_out[(size_t)(n0 + t) * F3 + g * 3 + d] = vl[t][g][d] + a_vv * uacc[t][d];
    }
}

// ---------------------------------------------------------------------------
extern "C" void kernel_launch(void* const* d_in, const int* in_sizes, int n_in,
                              void* d_out, int out_size, void* d_ws, size_t ws_size,
                              hipStream_t stream) {
    const float* s    = (const float*)d_in[0];
    const float* v    = (const float*)d_in[1];
    const float* rbf  = (const float*)d_in[2];
    const float* dir  = (const float*)d_in[3];
    const float* W1   = (const float*)d_in[4];
    const float* b1   = (const float*)d_in[5];
    const float* W2   = (const float*)d_in[6];
    const float* b2   = (const float*)d_in[7];
    const float* Wr   = (const float*)d_in[8];
    const float* br   = (const float*)d_in[9];
    const float* WU   = (const float*)d_in[10];
    const float* bU   = (const float*)d_in[11];
    const float* WV   = (const float*)d_in[12];
    const float* bV   = (const float*)d_in[13];
    const float* M1   = (const float*)d_in[14];
    const float* bm1  = (const float*)d_in[15];
    const float* M2   = (const float*)d_in[16];
    const float* bm2  = (const float*)d_in[17];
    const int* i_index = (const int*)d_in[18];
    const int* j_index = (const int*)d_in[19];

    float* out_s = (float*)d_out;                     // N*F
    float* out_v = out_s + (size_t)N_NODES * F;       // N*F*3

    // workspace layout
    float* h       = (float*)d_ws;                         // N*384 floats
    float* s_agg   = h + (size_t)N_NODES * F3;             // N*128
    float* v_agg   = s_agg + (size_t)N_NODES * F;          // N*384
    int*   counts  = (int*)(v_agg + (size_t)N_NODES * F3); // N
    int*   row_start = counts + N_NODES;                   // N+1
    int*   cursor  = row_start + N_NODES + 1;              // N
    int*   edge_ids = cursor + N_NODES;                    // E

    hipMemsetAsync(counts, 0, sizeof(int) * N_NODES, stream);

    node_mlp_kernel<<<N_NODES / NTILE_A, 128, 0, stream>>>(s, W1, b1, W2, b2, h);

    hist_kernel<<<(E_EDGES + 255) / 256, 256, 0, stream>>>(i_index, counts);
    scan_kernel<<<1, SCAN_T, 0, stream>>>(counts, row_start, cursor);
    scatter_kernel<<<(E_EDGES + 255) / 256, 256, 0, stream>>>(i_index, cursor, edge_ids);

    agg_kernel<<<N_NODES, 128, 0, stream>>>(s, v, rbf, dir, j_index, Wr, br, h,
                                            row_start, edge_ids, s_agg, v_agg);

    update_kernel<<<N_NODES / T_C, 128, 0, stream>>>(s_agg, v_agg, WU, bU, WV, bV,
                                                     M1, bm1, M2, bm2, out_s, out_v);
}